// Round 6
// baseline (37.178 us; speedup 1.0000x reference)
//
#include <hip/hip_runtime.h>
#include <math.h>
#include <stdint.h>

#define D_DIM 256
#define K_BINS 32
#define NCELL 512
#define NENT 34              // 32 bins + 2 sentinels
#define ENT_DW 12            // dwords per entry (48 B, 16B-aligned)
#define ENT_STRIDE 412       // dwords per dim in LDS (34*12 + 4 pad)
#define LIC_STRIDE 35        // floats per dim in LDS
#define LUT_BSTRIDE 516      // bytes per dim in LDS (512 + 4 pad)
#define SLICE 16             // dims per block

static constexpr float BOUND = 3.0f;
static constexpr float MIN_BIN_W = 1e-3f;
static constexpr float MIN_DERIV = 1e-3f;
static constexpr float MIN_LAMBDA = 0.025f;
static constexpr float EPS_ = 1e-6f;
static constexpr float CELL_W = 6.0f / NCELL;
static constexpr float CELL_S = NCELL / 6.0f;

__device__ __forceinline__ float softplusf_(float x) {
  return fmaxf(x, 0.0f) + log1pf(expf(-fabsf(x)));
}

// ---------------- precompute: unchanged from round 5 (verified) ----------------
__global__ void spline_precompute(const float* __restrict__ uw,
                                  const float* __restrict__ uh,
                                  const float* __restrict__ ud,
                                  const float* __restrict__ ul,
                                  float* __restrict__ tblg,
                                  float* __restrict__ licg,
                                  uint8_t* __restrict__ lutg,
                                  float* __restrict__ ldout,
                                  int B) {
  __shared__ float cw_lds[8][32];

  int tid = threadIdx.x;
  int gtid = blockIdx.x * 256 + tid;
  for (int i = gtid; i < B; i += 32 * 256) ldout[i] = 0.0f;

  int k = tid & 31;
  int dsub = tid >> 5;
  int d = blockIdx.x * 8 + dsub;

  float uwv = uw[d * K_BINS + k];
  float uhv = uh[d * K_BINS + k];
  float ulv = ul[d * K_BINS + k];
  float udv = (k < K_BINS - 1) ? ud[d * (K_BINS - 1) + k] : 0.0f;

  float wm = uwv, hm = uhv;
  for (int o = 16; o; o >>= 1) {
    wm = fmaxf(wm, __shfl_xor(wm, o, 32));
    hm = fmaxf(hm, __shfl_xor(hm, o, 32));
  }
  float ew = expf(uwv - wm), eh = expf(uhv - hm);
  float ws = ew, hs = eh;
  for (int o = 16; o; o >>= 1) {
    ws += __shfl_xor(ws, o, 32);
    hs += __shfl_xor(hs, o, 32);
  }
  const float kfac = 1.0f - MIN_BIN_W * (float)K_BINS;
  float sw = MIN_BIN_W + kfac * (ew / ws);
  float sh = MIN_BIN_W + kfac * (eh / hs);

  float cws = sw, chs = sh;
  for (int o = 1; o < 32; o <<= 1) {
    float tw = __shfl_up(cws, o, 32);
    float th = __shfl_up(chs, o, 32);
    if (k >= o) { cws += tw; chs += th; }
  }
  const float scale = 2.0f * BOUND;
  float raw_w = scale * cws - BOUND;
  float raw_h = scale * chs - BOUND;
  float upw = __shfl_up(raw_w, 1, 32);
  float uph = __shfl_up(raw_h, 1, 32);
  float cw_lo = (k == 0) ? -BOUND : upw;
  float ch_lo = (k == 0) ? -BOUND : uph;
  float cw_hi = (k == K_BINS - 1) ? BOUND : raw_w;
  float ch_hi = (k == K_BINS - 1) ? BOUND : raw_h;

  float iw = cw_hi - cw_lo;
  float ih = ch_hi - ch_lo;

  float dk = MIN_DERIV + softplusf_(udv);
  float dprev = __shfl_up(dk, 1, 32);
  float d1 = (k == K_BINS - 1) ? 1.0f : dk;
  float d0 = (k == 0) ? 1.0f : dprev;

  float sg = 1.0f / (1.0f + expf(-ulv));
  float lam = MIN_LAMBDA + (1.0f - 2.0f * MIN_LAMBDA) * sg;

  float wb = sqrtf(d0 / d1);
  float delta = ih / iw;
  float wc = (lam * d0 + (1.0f - lam) * wb * d1) / delta;
  float denom = (1.0f - lam) + lam * wb;
  float dyc = lam * wb * ih / denom;
  float dyb = ih - dyc;
  float ya = ch_lo;
  float inv_iw = 1.0f / iw;

  float* e = tblg + (size_t)(d * NENT + k) * ENT_DW;
  e[0] = cw_lo;
  e[1] = inv_iw;
  e[2] = lam;
  e[3] = wc;
  e[4] = wb;
  e[5] = wc * (ya + dyc);
  e[6] = wb * (ya + ih);
  e[7] = ya;
  e[8] = log2f(wc * lam * dyc * inv_iw);
  e[9] = log2f(wc * wb * (1.0f - lam) * dyb * inv_iw);
  e[10] = 0.0f;
  e[11] = 0.0f;
  licg[d * NENT + k] = cw_lo + EPS_;
  cw_lds[dsub][k] = cw_lo;

  if (tid < 8 * 2 * ENT_DW) {
    int dim = tid / (2 * ENT_DW);
    int r = tid - dim * (2 * ENT_DW);
    int ks = 32 + r / ENT_DW;
    int f = r - (r / ENT_DW) * ENT_DW;
    int dd = blockIdx.x * 8 + dim;
    tblg[((size_t)(dd * NENT + ks)) * ENT_DW + f] = (f == 0) ? 1e30f : 0.0f;
  }
  if (tid < 16) {
    int dim = tid >> 1;
    int ks = 32 + (tid & 1);
    licg[(blockIdx.x * 8 + dim) * NENT + ks] = 1e30f;
  }
  __syncthreads();

  for (int rep = 0; rep < 16; ++rep) {
    int idx = rep * 256 + tid;
    int dim = idx >> 9;
    int c = idx & (NCELL - 1);
    float L = fmaf((float)c, CELL_W, -BOUND) - 1e-5f;
    int j = 0;
#pragma unroll
    for (int st = 16; st >= 1; st >>= 1) {
      float cv = cw_lds[dim][j + st];
      j = (L >= cv + EPS_) ? j + st : j;
    }
    lutg[(blockIdx.x * 8 + dim) * NCELL + c] = (uint8_t)j;
  }
}

// per-element spline evaluation from LDS tables
__device__ __forceinline__ void spline_eval(
    float xv, const float* lent, const float* lic, const uint8_t* lutb,
    int entb, int licb, int lutbase, float& uu_out, float& lad2_out) {
  float xc = fminf(fmaxf(xv, -BOUND), BOUND);
  bool inside = fabsf(xv) <= BOUND;

  float cf = fmaf(xc, CELL_S, (float)(NCELL / 2));
  int c = (int)cf;
  c = min(c, NCELL - 1);
  int ilut = (int)lutb[lutbase + c];

  float c1 = lic[licb + ilut + 1];
  float c2 = lic[licb + ilut + 2];
  int idx = ilut + (xc >= c1 ? 1 : 0) + (xc >= c2 ? 1 : 0);

  int eb = entb + idx * ENT_DW;
  float4 A = *reinterpret_cast<const float4*>(&lent[eb]);
  float4 Bv = *reinterpret_cast<const float4*>(&lent[eb + 4]);
  float2 Lv = *reinterpret_cast<const float2*>(&lent[eb + 8]);

  float icw = A.x, inv_iw = A.y, il = A.z, wcv = A.w;
  float wbv = Bv.x, wcyc = Bv.y, wbyb = Bv.z, ya = Bv.w;

  float theta = (xc - icw) * inv_iw;
  bool lo = theta <= il;
  float t1 = il - theta;
  float t3 = 1.0f - theta;

  float n0 = lo ? ya : wcyc;
  float n1 = lo ? wcyc : wbyb;
  float p  = lo ? t1 : t3;
  float q  = lo ? theta : -t1;
  float dd0 = lo ? 1.0f : wcv;
  float dd1 = lo ? wcv : wbv;
  float Ls = lo ? Lv.x : Lv.y;

  float num = fmaf(n1, q, n0 * p);
  float den = fmaf(dd1, q, dd0 * p);
  float r = __builtin_amdgcn_rcpf(den);
  float uu = num * r;
  float lad2 = fmaf(-2.0f, __builtin_amdgcn_logf(den), Ls);

  uu_out = inside ? uu : xv;
  lad2_out = inside ? lad2 : 0.0f;
}

// 1024 blocks x 512 threads. Block owns 16 dims; XCD pair-swizzle puts the two
// blocks sharing each 128B x/u line on the same XCD. 2 rows/lane/iter + x prefetch.
__global__ __launch_bounds__(512) void spline_main(
    const float* __restrict__ x,
    const float* __restrict__ tblg,
    const float* __restrict__ licg,
    const uint8_t* __restrict__ lutg,
    float* __restrict__ uout,
    float* __restrict__ ldout,
    int B) {
  __shared__ float lent[SLICE * ENT_STRIDE];
  __shared__ float lic[SLICE * LIC_STRIDE];
  __shared__ uint8_t lutb[SLICE * LUT_BSTRIDE];

  int tid = threadIdx.x;
  // bid = pair*128 + odd*64 + group : blocks (group, 2t) and (group, 2t+1)
  // differ by 64 (== 0 mod 8) -> same XCD -> shared 128B lines dedup in L2.
  int bid = blockIdx.x;
  int pair = bid >> 7;
  int rem = bid & 127;
  int odd = rem >> 6;
  int group = rem & 63;
  int slice = pair * 2 + odd;
  int d0 = slice * SLICE;

  const float* esrc = tblg + (size_t)d0 * NENT * ENT_DW;
  for (int i = tid; i < SLICE * NENT * ENT_DW; i += 512) {
    int dim = i / (NENT * ENT_DW);
    int r2 = i - dim * (NENT * ENT_DW);
    lent[dim * ENT_STRIDE + r2] = esrc[i];
  }
  const float* lsrc = licg + (size_t)d0 * NENT;
  for (int i = tid; i < SLICE * NENT; i += 512) {
    int dim = i / NENT;
    int kk = i - dim * NENT;
    lic[dim * LIC_STRIDE + kk] = lsrc[i];
  }
  const uint32_t* lut32 = (const uint32_t*)(lutg + (size_t)d0 * NCELL);
  uint32_t* lutb32 = (uint32_t*)lutb;
  for (int i = tid; i < SLICE * (NCELL / 4); i += 512) {
    int dim = i >> 7;
    int w = i & 127;
    lutb32[dim * (LUT_BSTRIDE / 4) + w] = lut32[i];
  }
  __syncthreads();

  int lane = tid & 63;
  int wid = tid >> 6;
  int r4 = lane >> 4;
  int dsl = lane & 15;

  int row0 = group * 32 + wid * 4 + r4;          // [0, 2048)
  size_t baseA = (size_t)row0 * D_DIM + d0 + dsl; // rows row0 + it*2048, it<8
  size_t baseB = baseA + (size_t)16384 * D_DIM;   // second half of batch

  const int entb = dsl * ENT_STRIDE;
  const int licb = dsl * LIC_STRIDE;
  const int lutbase = dsl * LUT_BSTRIDE;
  const size_t ISTEP = (size_t)2048 * D_DIM;

  float xA = x[baseA];
  float xB = x[baseB];

#pragma unroll
  for (int it = 0; it < 8; ++it) {
    // prefetch next iteration's x (redundant re-read on last iter, harmless)
    int nx = (it < 7) ? it + 1 : 7;
    float pA = x[baseA + (size_t)nx * ISTEP];
    float pB = x[baseB + (size_t)nx * ISTEP];

    float uA, lA, uB, lB;
    spline_eval(xA, lent, lic, lutb, entb, licb, lutbase, uA, lA);
    spline_eval(xB, lent, lic, lutb, entb, licb, lutbase, uB, lB);

    size_t gA = baseA + (size_t)it * ISTEP;
    size_t gB = baseB + (size_t)it * ISTEP;
    uout[gA] = uA;
    uout[gB] = uB;

    // width-16 reduce over dims for both streams
    lA += __shfl_down(lA, 8, 16);
    lB += __shfl_down(lB, 8, 16);
    lA += __shfl_down(lA, 4, 16);
    lB += __shfl_down(lB, 4, 16);
    lA += __shfl_down(lA, 2, 16);
    lB += __shfl_down(lB, 2, 16);
    lA += __shfl_down(lA, 1, 16);
    lB += __shfl_down(lB, 1, 16);
    if (dsl == 0) {
      int rowA = row0 + (it << 11);
      atomicAdd(&ldout[rowA], lA * 0.69314718056f);
      atomicAdd(&ldout[rowA + 16384], lB * 0.69314718056f);
    }

    xA = pA;
    xB = pB;
  }
}

extern "C" void kernel_launch(void* const* d_in, const int* in_sizes, int n_in,
                              void* d_out, int out_size, void* d_ws, size_t ws_size,
                              hipStream_t stream) {
  const float* x  = (const float*)d_in[0];
  const float* uw = (const float*)d_in[1];
  const float* uh = (const float*)d_in[2];
  const float* ud = (const float*)d_in[3];
  const float* ul = (const float*)d_in[4];

  int B = in_sizes[0] / D_DIM;  // 32768

  float* out = (float*)d_out;
  float* uout = out;
  float* ldout = out + (size_t)B * D_DIM;

  char* ws = (char*)d_ws;
  float* tblg = (float*)ws;                        // 256*34*12*4 = 417792 B
  float* licg = (float*)(ws + 417792);             // 34816 B
  uint8_t* lutg = (uint8_t*)(ws + 417792 + 34816); // 131072 B

  spline_precompute<<<32, 256, 0, stream>>>(uw, uh, ud, ul, tblg, licg, lutg, ldout, B);
  spline_main<<<1024, 512, 0, stream>>>(x, tblg, licg, lutg, uout, ldout, B);
}

// Round 7
// 37.017 us; speedup vs baseline: 1.0043x; 1.0043x over previous
//
#include <hip/hip_runtime.h>
#include <math.h>
#include <stdint.h>

#define D_DIM 256
#define K_BINS 32
#define NCELL 512
#define NENT 34              // 32 bins + 2 sentinels
#define ENT_DW 12            // dwords per entry (48 B, 16B-aligned)
#define ENT_STRIDE 412       // dwords per dim in LDS (34*12 + 4 pad)
#define LIC_STRIDE 35        // floats per dim in LDS
#define LUT_BSTRIDE 516      // bytes per dim in LDS (512 + 4 pad)
#define SLICE 16             // dims per block

static constexpr float BOUND = 3.0f;
static constexpr float MIN_BIN_W = 1e-3f;
static constexpr float MIN_DERIV = 1e-3f;
static constexpr float MIN_LAMBDA = 0.025f;
static constexpr float EPS_ = 1e-6f;
static constexpr float CELL_W = 6.0f / NCELL;     // 0.01171875
static constexpr float CELL_S = NCELL / 6.0f;     // 85.333336f

__device__ __forceinline__ float softplusf_(float x) {
  return fmaxf(x, 0.0f) + log1pf(expf(-fabsf(x)));
}

// 32 blocks x 256 threads; block owns 8 dims (k = tid&31, dsub = tid>>5).
// Writes: tblg dense [d][34][12], licg dense [d][34] (= cw+eps, sentinels 1e30),
// lutg dense [d][512] u8, and zeroes ldout.
__global__ void spline_precompute(const float* __restrict__ uw,
                                  const float* __restrict__ uh,
                                  const float* __restrict__ ud,
                                  const float* __restrict__ ul,
                                  float* __restrict__ tblg,
                                  float* __restrict__ licg,
                                  uint8_t* __restrict__ lutg,
                                  float* __restrict__ ldout,
                                  int B) {
  __shared__ float cw_lds[8][32];

  int tid = threadIdx.x;
  int gtid = blockIdx.x * 256 + tid;
  for (int i = gtid; i < B; i += 32 * 256) ldout[i] = 0.0f;

  int k = tid & 31;
  int dsub = tid >> 5;
  int d = blockIdx.x * 8 + dsub;

  float uwv = uw[d * K_BINS + k];
  float uhv = uh[d * K_BINS + k];
  float ulv = ul[d * K_BINS + k];
  float udv = (k < K_BINS - 1) ? ud[d * (K_BINS - 1) + k] : 0.0f;

  // 32-lane softmax stats
  float wm = uwv, hm = uhv;
  for (int o = 16; o; o >>= 1) {
    wm = fmaxf(wm, __shfl_xor(wm, o, 32));
    hm = fmaxf(hm, __shfl_xor(hm, o, 32));
  }
  float ew = expf(uwv - wm), eh = expf(uhv - hm);
  float ws = ew, hs = eh;
  for (int o = 16; o; o >>= 1) {
    ws += __shfl_xor(ws, o, 32);
    hs += __shfl_xor(hs, o, 32);
  }
  const float kfac = 1.0f - MIN_BIN_W * (float)K_BINS;
  float sw = MIN_BIN_W + kfac * (ew / ws);
  float sh = MIN_BIN_W + kfac * (eh / hs);

  // inclusive 32-lane prefix sums
  float cws = sw, chs = sh;
  for (int o = 1; o < 32; o <<= 1) {
    float tw = __shfl_up(cws, o, 32);
    float th = __shfl_up(chs, o, 32);
    if (k >= o) { cws += tw; chs += th; }
  }
  const float scale = 2.0f * BOUND;
  float raw_w = scale * cws - BOUND;
  float raw_h = scale * chs - BOUND;
  float upw = __shfl_up(raw_w, 1, 32);
  float uph = __shfl_up(raw_h, 1, 32);
  float cw_lo = (k == 0) ? -BOUND : upw;
  float ch_lo = (k == 0) ? -BOUND : uph;
  float cw_hi = (k == K_BINS - 1) ? BOUND : raw_w;
  float ch_hi = (k == K_BINS - 1) ? BOUND : raw_h;

  float iw = cw_hi - cw_lo;
  float ih = ch_hi - ch_lo;

  float dk = MIN_DERIV + softplusf_(udv);
  float dprev = __shfl_up(dk, 1, 32);
  float d1 = (k == K_BINS - 1) ? 1.0f : dk;
  float d0 = (k == 0) ? 1.0f : dprev;

  float sg = 1.0f / (1.0f + expf(-ulv));
  float lam = MIN_LAMBDA + (1.0f - 2.0f * MIN_LAMBDA) * sg;

  float wb = sqrtf(d0 / d1);
  float delta = ih / iw;
  float wc = (lam * d0 + (1.0f - lam) * wb * d1) / delta;
  float denom = (1.0f - lam) + lam * wb;
  float dyc = lam * wb * ih / denom;   // yc - ya
  float dyb = ih - dyc;                // yb - yc
  float ya = ch_lo;
  float inv_iw = 1.0f / iw;

  float* e = tblg + (size_t)(d * NENT + k) * ENT_DW;
  e[0] = cw_lo;
  e[1] = inv_iw;
  e[2] = lam;
  e[3] = wc;
  e[4] = wb;
  e[5] = wc * (ya + dyc);   // wc*yc
  e[6] = wb * (ya + ih);    // wb*yb
  e[7] = ya;
  e[8] = log2f(wc * lam * dyc * inv_iw);            // L_lo
  e[9] = log2f(wc * wb * (1.0f - lam) * dyb * inv_iw); // L_hi
  e[10] = 0.0f;
  e[11] = 0.0f;
  licg[d * NENT + k] = cw_lo + EPS_;
  cw_lds[dsub][k] = cw_lo;

  // sentinel entries k=32,33: icw/lic = +inf-ish, rest 0
  if (tid < 8 * 2 * ENT_DW) {  // 192 threads
    int dim = tid / (2 * ENT_DW);
    int r = tid - dim * (2 * ENT_DW);
    int ks = 32 + r / ENT_DW;
    int f = r - (r / ENT_DW) * ENT_DW;
    int dd = blockIdx.x * 8 + dim;
    tblg[((size_t)(dd * NENT + ks)) * ENT_DW + f] = (f == 0) ? 1e30f : 0.0f;
  }
  if (tid < 16) {
    int dim = tid >> 1;
    int ks = 32 + (tid & 1);
    licg[(blockIdx.x * 8 + dim) * NENT + ks] = 1e30f;
  }
  __syncthreads();

  // LUT build: 8 dims x 512 cells, 16 cells/thread
  for (int rep = 0; rep < 16; ++rep) {
    int idx = rep * 256 + tid;
    int dim = idx >> 9;
    int c = idx & (NCELL - 1);
    float L = fmaf((float)c, CELL_W, -BOUND) - 1e-5f;
    int j = 0;
#pragma unroll
    for (int st = 16; st >= 1; st >>= 1) {
      float cv = cw_lds[dim][j + st];
      j = (L >= cv + EPS_) ? j + st : j;
    }
    lutg[(blockIdx.x * 8 + dim) * NCELL + c] = (uint8_t)j;
  }
}

// 1024 blocks x 512 threads (8 waves). Block owns 16 dims (slice = blk&15).
// Wave = 4 rows x 16 dims. LUT + refine (exact) + 12-dword entry in LDS.
__global__ __launch_bounds__(512, 8) void spline_main(
    const float* __restrict__ x,
    const float* __restrict__ tblg,
    const float* __restrict__ licg,
    const uint8_t* __restrict__ lutg,
    float* __restrict__ uout,
    float* __restrict__ ldout,
    int B) {
  __shared__ float lent[SLICE * ENT_STRIDE];     // 26368 B
  __shared__ float lic[SLICE * LIC_STRIDE];      // 2240 B
  __shared__ uint8_t lutb[SLICE * LUT_BSTRIDE];  // 8256 B

  int tid = threadIdx.x;
  int slice = blockIdx.x & 15;
  int group = blockIdx.x >> 4;   // 0..63
  int d0 = slice * SLICE;

  // stage entries (dense [dim][34][12] -> padded stride 412)
  const float* esrc = tblg + (size_t)d0 * NENT * ENT_DW;
  for (int i = tid; i < SLICE * NENT * ENT_DW; i += 512) {
    int dim = i / (NENT * ENT_DW);
    int rem = i - dim * (NENT * ENT_DW);
    lent[dim * ENT_STRIDE + rem] = esrc[i];
  }
  // stage lic (dense [dim][34] -> stride 35)
  const float* lsrc = licg + (size_t)d0 * NENT;
  for (int i = tid; i < SLICE * NENT; i += 512) {
    int dim = i / NENT;
    int kk = i - dim * NENT;
    lic[dim * LIC_STRIDE + kk] = lsrc[i];
  }
  // stage LUT as dwords (dense [dim][512]B -> stride 516B)
  const uint32_t* lut32 = (const uint32_t*)(lutg + (size_t)d0 * NCELL);
  uint32_t* lutb32 = (uint32_t*)lutb;
  for (int i = tid; i < SLICE * (NCELL / 4); i += 512) {
    int dim = i >> 7;
    int w = i & 127;
    lutb32[dim * (LUT_BSTRIDE / 4) + w] = lut32[i];
  }
  __syncthreads();

  int lane = tid & 63;
  int wid = tid >> 6;
  int r4 = lane >> 4;
  int dsl = lane & 15;

  int row0 = group * 32 + wid * 4 + r4;
  size_t base = (size_t)row0 * D_DIM + d0 + dsl;
  const int entb = dsl * ENT_STRIDE;
  const int licb = dsl * LIC_STRIDE;
  const int lutbase = dsl * LUT_BSTRIDE;

  int niter = B >> 11;  // B / 2048
  for (int it = 0; it < niter; ++it) {
    int row = row0 + (it << 11);
    size_t gidx = base + ((size_t)it << 11) * D_DIM;

    float xv = x[gidx];
    float xc = fminf(fmaxf(xv, -BOUND), BOUND);   // v_med3
    bool inside = fabsf(xv) <= BOUND;

    // cell -> LUT -> 2 exact refine steps
    float cf = fmaf(xc, CELL_S, (float)(NCELL / 2));
    int c = (int)cf;
    c = min(c, NCELL - 1);
    int ilut = (int)lutb[lutbase + c];

    float c1 = lic[licb + ilut + 1];   // cw+eps, sentinel-safe
    float c2 = lic[licb + ilut + 2];
    int idx = ilut + (xc >= c1 ? 1 : 0) + (xc >= c2 ? 1 : 0);

    int eb = entb + idx * ENT_DW;
    float4 A = *reinterpret_cast<const float4*>(&lent[eb]);      // icw,inv_iw,il,wc
    float4 Bv = *reinterpret_cast<const float4*>(&lent[eb + 4]); // wb,wcyc,wbyb,ya
    float2 Lv = *reinterpret_cast<const float2*>(&lent[eb + 8]); // L_lo,L_hi

    float icw = A.x, inv_iw = A.y, il = A.z, wcv = A.w;
    float wbv = Bv.x, wcyc = Bv.y, wbyb = Bv.z, ya = Bv.w;

    float theta = (xc - icw) * inv_iw;
    bool lo = theta <= il;
    float t1 = il - theta;
    float t3 = 1.0f - theta;

    float n0 = lo ? ya : wcyc;
    float n1 = lo ? wcyc : wbyb;
    float p  = lo ? t1 : t3;
    float q  = lo ? theta : -t1;
    float dd0 = lo ? 1.0f : wcv;
    float dd1 = lo ? wcv : wbv;
    float Ls = lo ? Lv.x : Lv.y;

    float num = fmaf(n1, q, n0 * p);
    float den = fmaf(dd1, q, dd0 * p);
    float r = __builtin_amdgcn_rcpf(den);
    float uu = num * r;
    float lad2 = fmaf(-2.0f, __builtin_amdgcn_logf(den), Ls);  // log2 units

    uout[gidx] = inside ? uu : xv;
    float ls = inside ? lad2 : 0.0f;

    // width-16 reduce over dims, then one fire-and-forget atomic per row
    ls += __shfl_down(ls, 8, 16);
    ls += __shfl_down(ls, 4, 16);
    ls += __shfl_down(ls, 2, 16);
    ls += __shfl_down(ls, 1, 16);
    if (dsl == 0) atomicAdd(&ldout[row], ls * 0.69314718056f);
  }
}

extern "C" void kernel_launch(void* const* d_in, const int* in_sizes, int n_in,
                              void* d_out, int out_size, void* d_ws, size_t ws_size,
                              hipStream_t stream) {
  const float* x  = (const float*)d_in[0];
  const float* uw = (const float*)d_in[1];
  const float* uh = (const float*)d_in[2];
  const float* ud = (const float*)d_in[3];
  const float* ul = (const float*)d_in[4];

  int B = in_sizes[0] / D_DIM;  // 32768

  float* out = (float*)d_out;
  float* uout = out;
  float* ldout = out + (size_t)B * D_DIM;

  char* ws = (char*)d_ws;
  float* tblg = (float*)ws;                                  // 256*34*12*4 = 417792 B
  float* licg = (float*)(ws + 417792);                       // 256*34*4   = 34816 B
  uint8_t* lutg = (uint8_t*)(ws + 417792 + 34816);           // 256*512    = 131072 B

  spline_precompute<<<32, 256, 0, stream>>>(uw, uh, ud, ul, tblg, licg, lutg, ldout, B);
  spline_main<<<1024, 512, 0, stream>>>(x, tblg, licg, lutg, uout, ldout, B);
}

// Round 8
// 34.051 us; speedup vs baseline: 1.0918x; 1.0871x over previous
//
#include <hip/hip_runtime.h>
#include <hip/hip_fp16.h>
#include <math.h>
#include <stdint.h>

#define D_DIM 256
#define K_BINS 32
#define NCELL 512
#define NENT 34              // 32 bins + 2 sentinels
#define ENT_DW 8             // dwords per entry (32 B, two float4)
#define ENT_STRIDE 276       // dwords per dim in LDS (34*8 + 4 pad; 276/4=69 ≡ 5 mod 8)
#define LIC_STRIDE 35        // floats per dim in LDS
#define LUT_BSTRIDE 516      // bytes per dim in LDS (512 + 4 pad)
#define SLICE 16             // dims per block

static constexpr float BOUND = 3.0f;
static constexpr float MIN_BIN_W = 1e-3f;
static constexpr float MIN_DERIV = 1e-3f;
static constexpr float MIN_LAMBDA = 0.025f;
static constexpr float EPS_ = 1e-6f;
static constexpr float CELL_W = 6.0f / NCELL;
static constexpr float CELL_S = NCELL / 6.0f;
static constexpr float LN2_ = 0.69314718055994531f;

__device__ __forceinline__ float softplusf_(float x) {
  return fmaxf(x, 0.0f) + log1pf(expf(-fabsf(x)));
}

__device__ __forceinline__ float pack2h_as_f32(float a, float b) {
  __half2 h = __halves2half2(__float2half_rn(a), __float2half_rn(b));
  union { __half2 h; uint32_t u; } c;
  c.h = h;
  return __uint_as_float(c.u);
}

__device__ __forceinline__ float2 unpack2h_from_f32(float v) {
  union { uint32_t u; __half2 h; } c;
  c.u = __float_as_uint(v);
  return make_float2(__low2float(c.h), __high2float(c.h));
}

// 32 blocks x 256 threads; block owns 8 dims (k = tid&31, dsub = tid>>5).
// Entry (8 dw): [icw][inv_iw][lam][wc] [wb][yc][f16x2 dyc,dyb][f16x2 Llo,Lhi]
__global__ void spline_precompute(const float* __restrict__ uw,
                                  const float* __restrict__ uh,
                                  const float* __restrict__ ud,
                                  const float* __restrict__ ul,
                                  float* __restrict__ tblg,
                                  float* __restrict__ licg,
                                  uint8_t* __restrict__ lutg) {
  __shared__ float cw_lds[8][32];

  int tid = threadIdx.x;
  int k = tid & 31;
  int dsub = tid >> 5;
  int d = blockIdx.x * 8 + dsub;

  float uwv = uw[d * K_BINS + k];
  float uhv = uh[d * K_BINS + k];
  float ulv = ul[d * K_BINS + k];
  float udv = (k < K_BINS - 1) ? ud[d * (K_BINS - 1) + k] : 0.0f;

  // 32-lane softmax stats
  float wm = uwv, hm = uhv;
  for (int o = 16; o; o >>= 1) {
    wm = fmaxf(wm, __shfl_xor(wm, o, 32));
    hm = fmaxf(hm, __shfl_xor(hm, o, 32));
  }
  float ew = expf(uwv - wm), eh = expf(uhv - hm);
  float ws = ew, hs = eh;
  for (int o = 16; o; o >>= 1) {
    ws += __shfl_xor(ws, o, 32);
    hs += __shfl_xor(hs, o, 32);
  }
  const float kfac = 1.0f - MIN_BIN_W * (float)K_BINS;
  float sw = MIN_BIN_W + kfac * (ew / ws);
  float sh = MIN_BIN_W + kfac * (eh / hs);

  // inclusive 32-lane prefix sums
  float cws = sw, chs = sh;
  for (int o = 1; o < 32; o <<= 1) {
    float tw = __shfl_up(cws, o, 32);
    float th = __shfl_up(chs, o, 32);
    if (k >= o) { cws += tw; chs += th; }
  }
  const float scale = 2.0f * BOUND;
  float raw_w = scale * cws - BOUND;
  float raw_h = scale * chs - BOUND;
  float upw = __shfl_up(raw_w, 1, 32);
  float uph = __shfl_up(raw_h, 1, 32);
  float cw_lo = (k == 0) ? -BOUND : upw;
  float ch_lo = (k == 0) ? -BOUND : uph;
  float cw_hi = (k == K_BINS - 1) ? BOUND : raw_w;
  float ch_hi = (k == K_BINS - 1) ? BOUND : raw_h;

  float iw = cw_hi - cw_lo;
  float ih = ch_hi - ch_lo;

  float dk = MIN_DERIV + softplusf_(udv);
  float dprev = __shfl_up(dk, 1, 32);
  float d1 = (k == K_BINS - 1) ? 1.0f : dk;
  float d0 = (k == 0) ? 1.0f : dprev;

  float sg = 1.0f / (1.0f + expf(-ulv));
  float lam = MIN_LAMBDA + (1.0f - 2.0f * MIN_LAMBDA) * sg;

  float wb = sqrtf(d0 / d1);
  float delta = ih / iw;
  float wc = (lam * d0 + (1.0f - lam) * wb * d1) / delta;
  float denom = (1.0f - lam) + lam * wb;
  float dyc = lam * wb * ih / denom;   // yc - ya
  float dyb = ih - dyc;                // yb - yc
  float ya = ch_lo;
  float inv_iw = 1.0f / iw;
  float yc = ya + dyc;

  float* e = tblg + (size_t)(d * NENT + k) * ENT_DW;
  e[0] = cw_lo;
  e[1] = inv_iw;
  e[2] = lam;
  e[3] = wc;
  e[4] = wb;
  e[5] = yc;
  e[6] = pack2h_as_f32(dyc, dyb);
  e[7] = pack2h_as_f32(log2f(wc * lam * dyc * inv_iw),
                       log2f(wc * wb * (1.0f - lam) * dyb * inv_iw));
  licg[d * NENT + k] = cw_lo + EPS_;
  cw_lds[dsub][k] = cw_lo;

  // sentinel entries k=32,33
  if (tid < 8 * 2 * ENT_DW) {  // 128 threads
    int dim = tid >> 4;        // /16
    int r = tid & 15;
    int ks = 32 + (r >> 3);
    int f = r & 7;
    int dd = blockIdx.x * 8 + dim;
    tblg[((size_t)(dd * NENT + ks)) * ENT_DW + f] = (f == 0) ? 1e30f : 0.0f;
  }
  if (tid < 16) {
    int dim = tid >> 1;
    int ks = 32 + (tid & 1);
    licg[(blockIdx.x * 8 + dim) * NENT + ks] = 1e30f;
  }
  __syncthreads();

  // LUT build: 8 dims x 512 cells, 16 cells/thread
  for (int rep = 0; rep < 16; ++rep) {
    int idx = rep * 256 + tid;
    int dim = idx >> 9;
    int c = idx & (NCELL - 1);
    float L = fmaf((float)c, CELL_W, -BOUND) - 1e-5f;
    int j = 0;
#pragma unroll
    for (int st = 16; st >= 1; st >>= 1) {
      float cv = cw_lds[dim][j + st];
      j = (L >= cv + EPS_) ? j + st : j;
    }
    lutg[(blockIdx.x * 8 + dim) * NCELL + c] = (uint8_t)j;
  }
}

// 1024 blocks x 512 threads (8 waves). Block owns 16 dims (slice = blk&15).
// Wave = 4 rows x 16 dims. No atomics: per-(slice,row) partials to `part`.
__global__ __launch_bounds__(512, 8) void spline_main(
    const float* __restrict__ x,
    const float* __restrict__ tblg,
    const float* __restrict__ licg,
    const uint8_t* __restrict__ lutg,
    float* __restrict__ uout,
    float* __restrict__ part,
    int B) {
  __shared__ float lent[SLICE * ENT_STRIDE];     // 17664 B
  __shared__ float lic[SLICE * LIC_STRIDE];      // 2240 B
  __shared__ uint8_t lutb[SLICE * LUT_BSTRIDE];  // 8256 B

  int tid = threadIdx.x;
  int slice = blockIdx.x & 15;
  int group = blockIdx.x >> 4;   // 0..63
  int d0 = slice * SLICE;

  // stage entries (dense [dim][34][8] -> padded stride 276)
  const float* esrc = tblg + (size_t)d0 * NENT * ENT_DW;
  for (int i = tid; i < SLICE * NENT * ENT_DW; i += 512) {
    int dim = i / (NENT * ENT_DW);
    int rem = i - dim * (NENT * ENT_DW);
    lent[dim * ENT_STRIDE + rem] = esrc[i];
  }
  // stage lic (dense [dim][34] -> stride 35)
  const float* lsrc = licg + (size_t)d0 * NENT;
  for (int i = tid; i < SLICE * NENT; i += 512) {
    int dim = i / NENT;
    int kk = i - dim * NENT;
    lic[dim * LIC_STRIDE + kk] = lsrc[i];
  }
  // stage LUT as dwords
  const uint32_t* lut32 = (const uint32_t*)(lutg + (size_t)d0 * NCELL);
  uint32_t* lutb32 = (uint32_t*)lutb;
  for (int i = tid; i < SLICE * (NCELL / 4); i += 512) {
    int dim = i >> 7;
    int w = i & 127;
    lutb32[dim * (LUT_BSTRIDE / 4) + w] = lut32[i];
  }
  __syncthreads();

  int lane = tid & 63;
  int wid = tid >> 6;
  int r4 = lane >> 4;
  int dsl = lane & 15;

  int row0 = group * 32 + wid * 4 + r4;
  size_t base = (size_t)row0 * D_DIM + d0 + dsl;
  const int entb = dsl * ENT_STRIDE;
  const int licb = dsl * LIC_STRIDE;
  const int lutbase = dsl * LUT_BSTRIDE;
  float* parts = part + (size_t)slice * B;

  int niter = B >> 11;  // B / 2048
  for (int it = 0; it < niter; ++it) {
    int row = row0 + (it << 11);
    size_t gidx = base + ((size_t)it << 11) * D_DIM;

    float xv = x[gidx];
    float xc = fminf(fmaxf(xv, -BOUND), BOUND);
    bool inside = fabsf(xv) <= BOUND;

    // cell -> LUT -> 2 exact refine steps
    float cf = fmaf(xc, CELL_S, (float)(NCELL / 2));
    int c = (int)cf;
    c = min(c, NCELL - 1);
    int ilut = (int)lutb[lutbase + c];

    float c1 = lic[licb + ilut + 1];
    float c2 = lic[licb + ilut + 2];
    int idx = ilut + (xc >= c1 ? 1 : 0) + (xc >= c2 ? 1 : 0);

    int eb = entb + idx * ENT_DW;
    float4 A = *reinterpret_cast<const float4*>(&lent[eb]);      // icw,inv_iw,il,wc
    float4 Bv = *reinterpret_cast<const float4*>(&lent[eb + 4]); // wb,yc,dycdyb,LL

    float icw = A.x, inv_iw = A.y, il = A.z, wcv = A.w;
    float wbv = Bv.x, yc = Bv.y;
    float2 dd = unpack2h_from_f32(Bv.z);   // dyc, dyb
    float2 LL = unpack2h_from_f32(Bv.w);   // Llo, Lhi

    float theta = (xc - icw) * inv_iw;
    bool lo = theta <= il;
    float t1 = il - theta;                 // >=0 in lo branch; t4 = -t1
    float t3 = 1.0f - theta;

    float den = lo ? fmaf(wcv, theta, t1)
                   : fmaf(wcv, t3, -(wbv * t1));
    float sfac = lo ? dd.x : (wbv * dd.y);
    float Ls = lo ? LL.x : LL.y;

    float r = __builtin_amdgcn_rcpf(den);
    float uu = fmaf(-t1 * sfac, r, yc);
    float lad2 = fmaf(-2.0f, __builtin_amdgcn_logf(den), Ls);  // log2 units

    uout[gidx] = inside ? uu : xv;
    float ls = inside ? lad2 : 0.0f;

    // width-16 reduce over dims, then one plain store per (slice,row)
    ls += __shfl_down(ls, 8, 16);
    ls += __shfl_down(ls, 4, 16);
    ls += __shfl_down(ls, 2, 16);
    ls += __shfl_down(ls, 1, 16);
    if (dsl == 0) parts[row] = ls;
  }
}

// 128 blocks x 256 threads: ldout[row] = ln2 * sum_s part[s][row]
__global__ void spline_reduce(const float* __restrict__ part,
                              float* __restrict__ ldout, int B) {
  int row = blockIdx.x * 256 + threadIdx.x;
  if (row >= B) return;
  float s = 0.0f;
#pragma unroll
  for (int sl = 0; sl < D_DIM / SLICE; ++sl) s += part[(size_t)sl * B + row];
  ldout[row] = s * LN2_;
}

extern "C" void kernel_launch(void* const* d_in, const int* in_sizes, int n_in,
                              void* d_out, int out_size, void* d_ws, size_t ws_size,
                              hipStream_t stream) {
  const float* x  = (const float*)d_in[0];
  const float* uw = (const float*)d_in[1];
  const float* uh = (const float*)d_in[2];
  const float* ud = (const float*)d_in[3];
  const float* ul = (const float*)d_in[4];

  int B = in_sizes[0] / D_DIM;  // 32768

  float* out = (float*)d_out;
  float* uout = out;
  float* ldout = out + (size_t)B * D_DIM;

  char* ws = (char*)d_ws;
  float* tblg = (float*)ws;                                  // 256*34*8*4 = 278528 B
  float* licg = (float*)(ws + 278528);                       // 34816 B
  uint8_t* lutg = (uint8_t*)(ws + 278528 + 34816);           // 131072 B
  float* part = (float*)(ws + 278528 + 34816 + 131072);      // 16*B*4 = 2 MB

  spline_precompute<<<32, 256, 0, stream>>>(uw, uh, ud, ul, tblg, licg, lutg);
  spline_main<<<1024, 512, 0, stream>>>(x, tblg, licg, lutg, uout, part, B);
  spline_reduce<<<(B + 255) / 256, 256, 0, stream>>>(part, ldout, B);
}